// Round 7
// baseline (1558.926 us; speedup 1.0000x reference)
//
#include <hip/hip_runtime.h>
#include <cstdint>
#include <cstddef>

#define NN 50000
#define NE 800000
#define NG 64
#define IND 768
#define HID 256
#define NREL 3
#define NLAY 3

typedef __attribute__((ext_vector_type(4))) float f32x4;
typedef __attribute__((ext_vector_type(8))) short s16x8;

// ---------------- utility ----------------
__global__ void k_zero_int(int* __restrict__ p, int n) {
  int i = blockIdx.x * 256 + threadIdx.x;
  if (i < n) p[i] = 0;
}

__global__ void k_hist(const int* __restrict__ dst, int* __restrict__ deg) {
  int e = blockIdx.x * 256 + threadIdx.x;
  if (e < NE) atomicAdd(&deg[dst[e]], 1);
}

__global__ __launch_bounds__(1024) void k_scan(const int* __restrict__ deg,
                                               int* __restrict__ row_start,
                                               int* __restrict__ cursor) {
  __shared__ int wsum[16];
  int t = threadIdx.x;
  int lane = t & 63, wid = t >> 6;
  int running = 0;
  if (t == 0) row_start[0] = 0;
  for (int base = 0; base < NN; base += 4096) {
    int idx = base + t * 4;
    int4 d = *(const int4*)(deg + idx);
    int s = d.x + d.y + d.z + d.w;
    int sc = s;
    #pragma unroll
    for (int off = 1; off < 64; off <<= 1) {
      int o = __shfl_up(sc, off);
      if (lane >= off) sc += o;
    }
    if (lane == 63) wsum[wid] = sc;
    __syncthreads();
    if (t == 0) {
      int a = 0;
      #pragma unroll
      for (int i = 0; i < 16; ++i) { a += wsum[i]; wsum[i] = a; }
    }
    __syncthreads();
    int woff = (wid == 0) ? 0 : wsum[wid - 1];
    int excl = running + woff + (sc - s);
    int e0 = excl, e1 = e0 + d.x, e2 = e1 + d.y, e3 = e2 + d.z, e4 = e3 + d.w;
    if (idx     < NN) { cursor[idx]     = e0; row_start[idx + 1] = e1; }
    if (idx + 1 < NN) { cursor[idx + 1] = e1; row_start[idx + 2] = e2; }
    if (idx + 2 < NN) { cursor[idx + 2] = e2; row_start[idx + 3] = e3; }
    if (idx + 3 < NN) { cursor[idx + 3] = e3; row_start[idx + 4] = e4; }
    running += wsum[15];
    __syncthreads();
  }
}

__global__ void k_scatter(const int* __restrict__ src, const int* __restrict__ dst,
                          const int* __restrict__ ety, int* __restrict__ cursor,
                          unsigned* __restrict__ csr) {
  int e = blockIdx.x * 256 + threadIdx.x;
  if (e >= NE) return;
  int pos = atomicAdd(&cursor[dst[e]], 1);
  csr[pos] = (unsigned)src[e] | ((unsigned)ety[e] << 16);
}

__global__ void k_graph_bounds(const int* __restrict__ batch, int* __restrict__ gstart) {
  int i = blockIdx.x * 256 + threadIdx.x;
  if (i >= NN) return;
  int b = batch[i];
  int bp = (i == 0) ? -1 : batch[i - 1];
  for (int g = bp + 1; g <= b; ++g) gstart[g] = i;
  if (i == NN - 1) {
    for (int g = b + 1; g <= NG; ++g) gstart[g] = NN;
  }
}

// ---------------- aggregation ----------------
// one 64-thread block per node; thread t owns channels [4t,4t+4).
// Edge loop unrolled x4 with batched gathers: 4 independent 1KB row reads
// in flight per wave (L3 latency-bound otherwise).
__global__ __launch_bounds__(64) void k_aggregate(const float* __restrict__ h,
                                                  const int* __restrict__ row_start,
                                                  const unsigned* __restrict__ csr,
                                                  float* __restrict__ agg) {
  int n = blockIdx.x;
  int t = threadIdx.x;
  int s = row_start[n], e = row_start[n + 1];
  float4 a0 = {0, 0, 0, 0}, a1 = {0, 0, 0, 0}, a2 = {0, 0, 0, 0};
  int c0 = 0, c1 = 0, c2 = 0;
  __shared__ unsigned buf[64];
  auto accum = [&](unsigned p, float4 v) {
    int ty = (int)(p >> 16);   // wave-uniform
    if (ty == 0)      { a0.x += v.x; a0.y += v.y; a0.z += v.z; a0.w += v.w; c0++; }
    else if (ty == 1) { a1.x += v.x; a1.y += v.y; a1.z += v.z; a1.w += v.w; c1++; }
    else              { a2.x += v.x; a2.y += v.y; a2.z += v.z; a2.w += v.w; c2++; }
  };
  for (int base = s; base < e; base += 64) {
    int m = e - base; if (m > 64) m = 64;
    __syncthreads();
    if (t < m) buf[t] = csr[base + t];
    __syncthreads();
    int j = 0;
    for (; j + 4 <= m; j += 4) {
      unsigned p0 = buf[j], p1 = buf[j + 1], p2 = buf[j + 2], p3 = buf[j + 3];
      float4 v0 = *(const float4*)(h + (size_t)(p0 & 0xFFFF) * HID + t * 4);
      float4 v1 = *(const float4*)(h + (size_t)(p1 & 0xFFFF) * HID + t * 4);
      float4 v2 = *(const float4*)(h + (size_t)(p2 & 0xFFFF) * HID + t * 4);
      float4 v3 = *(const float4*)(h + (size_t)(p3 & 0xFFFF) * HID + t * 4);
      accum(p0, v0); accum(p1, v1); accum(p2, v2); accum(p3, v3);
    }
    for (; j < m; ++j) {
      unsigned p = buf[j];
      float4 v = *(const float4*)(h + (size_t)(p & 0xFFFF) * HID + t * 4);
      accum(p, v);
    }
  }
  float i0 = 1.f / (float)(c0 > 1 ? c0 : 1);
  float i1 = 1.f / (float)(c1 > 1 ? c1 : 1);
  float i2 = 1.f / (float)(c2 > 1 ? c2 : 1);
  float* o = agg + (size_t)n * (NREL * HID) + t * 4;
  float4 r0 = {a0.x * i0, a0.y * i0, a0.z * i0, a0.w * i0};
  float4 r1 = {a1.x * i1, a1.y * i1, a1.z * i1, a1.w * i1};
  float4 r2 = {a2.x * i2, a2.y * i2, a2.z * i2, a2.w * i2};
  *(float4*)(o)           = r0;
  *(float4*)(o + HID)     = r1;
  *(float4*)(o + 2 * HID) = r2;
}

// ---------------- bf16 split helpers ----------------
__device__ __forceinline__ unsigned short bf16rne(float f) {
  union { float f; unsigned u; } x; x.f = f;
  unsigned r = (x.u + 0x7FFFu + ((x.u >> 16) & 1u)) >> 16;
  return (unsigned short)r;
}
__device__ __forceinline__ float bf2f(unsigned short h) {
  union { unsigned u; float f; } x; x.u = ((unsigned)h) << 16;
  return x.f;
}

__global__ void k_cvt(const float* __restrict__ s1, int K1e,
                      const float* __restrict__ s2, int Ktot,
                      unsigned short* __restrict__ hi, unsigned short* __restrict__ lo) {
  int t = blockIdx.x * 256 + threadIdx.x;
  if (t >= Ktot * 256) return;
  int c = t & 255, k = t >> 8;
  float v = (k < K1e) ? s1[(size_t)k * 256 + c] : s2[(size_t)(k - K1e) * 256 + c];
  unsigned short h = bf16rne(v);
  unsigned short l = bf16rne(v - bf2f(h));
  size_t o = ((size_t)(k >> 3) * 256 + c) * 8 + (k & 7);
  hi[o] = h; lo[o] = l;
}

__device__ __forceinline__ void load_lds16b(const void* g, void* l) {
  __builtin_amdgcn_global_load_lds(
      (const __attribute__((address_space(1))) unsigned*)g,
      (__attribute__((address_space(3))) unsigned*)l, 16, 0, 0);
}

// ---------------- MFMA GEMM (fp32 via 3-term bf16 split) ----------------
// A LDS layout [koct][row ^ (koct<<2)][8]: XOR swizzle makes the b128 writes
// 2-way (free) instead of 4-way same-bank, reads stay contiguous-256B clean.
// Next A-tile register prefetch issued after frag reads -> latency hides
// under the 192-MFMA compute phase.
template <int EPI>
__global__ __launch_bounds__(256, 1) void k_gemm_mfma(
    const float* __restrict__ A1, int lda1,
    const float* __restrict__ A2, int lda2, int K1,
    const unsigned short* __restrict__ Bhi, const unsigned short* __restrict__ Blo,
    const float* __restrict__ bias, const float* __restrict__ res,
    const float* __restrict__ lnw, const float* __restrict__ lnb,
    float* __restrict__ C, int M, int K) {
  __shared__ __align__(16) unsigned short AsH[4 * 64 * 8], AsL[4 * 64 * 8];   // 4KB each
  __shared__ __align__(16) unsigned short BsH[4 * 256 * 8], BsL[4 * 256 * 8]; // 16KB each
  __shared__ float lnred[64 * 4 * 2];                                         // 2KB
  int tid = (int)threadIdx.x;
  int lane = tid & 63, wv = tid >> 6;
  int n0 = (int)blockIdx.x * 64;
  int srow = tid >> 2, sg = tid & 3;
  int grow = n0 + srow; if (grow > M - 1) grow = M - 1;
  int c16 = lane & 15, kg = lane >> 4;
  int col0 = wv * 64;

  f32x4 acc[4][4] = {};
  int nkt = K / 32;

  float4 a0, a1;
  {  // prologue: A tile 0 (K1 > 0 always here)
    const float* ap = A1 + (size_t)grow * lda1 + sg * 8;
    a0 = *(const float4*)ap;
    a1 = *(const float4*)(ap + 4);
  }

  for (int kt = 0; kt < nkt; ++kt) {
    __syncthreads();   // prior tile's frag reads complete
    // B: global->LDS DMA, 8 issues/wave, 1KB each, linear
    #pragma unroll
    for (int i = 0; i < 8; ++i) {
      int id = wv * 8 + i;
      const unsigned short* srcp = (id < 16) ? Bhi : Blo;
      unsigned short* dstp = (id < 16) ? BsH : BsL;
      int rem = id & 15, g = rem >> 2, ch = rem & 3;
      load_lds16b(srcp + (size_t)(kt * 4 + g) * 2048 + (ch * 64 + lane) * 8,
                  dstp + (g * 256 + ch * 64) * 8);
    }
    // A: split to bf16 hi/lo, swizzled store
    {
      float va[8] = {a0.x, a0.y, a0.z, a0.w, a1.x, a1.y, a1.z, a1.w};
      s16x8 hv, lv;
      #pragma unroll
      for (int j = 0; j < 8; ++j) {
        unsigned short h = bf16rne(va[j]);
        hv[j] = (short)h;
        lv[j] = (short)bf16rne(va[j] - bf2f(h));
      }
      int aoff = (sg * 64 + (srow ^ (sg << 2))) * 8;
      *(s16x8*)&AsH[aoff] = hv;
      *(s16x8*)&AsL[aoff] = lv;
    }
    __syncthreads();   // drains vmcnt (B DMA) + lgkm (A writes)
    // fragments
    s16x8 ah[4], al[4];
    #pragma unroll
    for (int ri = 0; ri < 4; ++ri) {
      int ao = (kg * 64 + ((ri * 16 + c16) ^ (kg << 2))) * 8;
      ah[ri] = *(const s16x8*)&AsH[ao];
      al[ri] = *(const s16x8*)&AsL[ao];
    }
    // prefetch next A tile (latency hidden under MFMA)
    int kn = (kt + 1) * 32;
    if (kn < K) {
      const float* Ap; int ld, kc;
      if (kn < K1) { Ap = A1; ld = lda1; kc = kn; }
      else         { Ap = A2; ld = lda2; kc = kn - K1; }
      const float* ap = Ap + (size_t)grow * ld + kc + sg * 8;
      a0 = *(const float4*)ap;
      a1 = *(const float4*)(ap + 4);
    }
    #pragma unroll
    for (int ci = 0; ci < 4; ++ci) {
      int bo = (kg * 256 + col0 + ci * 16 + c16) * 8;
      s16x8 bh = *(const s16x8*)&BsH[bo];
      s16x8 bl = *(const s16x8*)&BsL[bo];
      #pragma unroll
      for (int ri = 0; ri < 4; ++ri) {
        acc[ri][ci] = __builtin_amdgcn_mfma_f32_16x16x32_bf16(ah[ri], bh, acc[ri][ci], 0, 0, 0);
        acc[ri][ci] = __builtin_amdgcn_mfma_f32_16x16x32_bf16(ah[ri], bl, acc[ri][ci], 0, 0, 0);
        acc[ri][ci] = __builtin_amdgcn_mfma_f32_16x16x32_bf16(al[ri], bh, acc[ri][ci], 0, 0, 0);
      }
    }
  }

  // ---------------- epilogue ----------------
  // C/D layout: col = lane&15, row = (lane>>4)*4 + reg
  float bw[4], lw[4], lb[4];
  #pragma unroll
  for (int ci = 0; ci < 4; ++ci) {
    int col = col0 + ci * 16 + c16;
    bw[ci] = bias[col];
    if (EPI == 1) { lw[ci] = lnw[col]; lb[ci] = lnb[col]; }
  }
  if (EPI == 0) {
    #pragma unroll
    for (int ri = 0; ri < 4; ++ri)
      #pragma unroll
      for (int q = 0; q < 4; ++q) {
        int row = n0 + ri * 16 + kg * 4 + q;
        if (row < M) {
          #pragma unroll
          for (int ci = 0; ci < 4; ++ci)
            C[(size_t)row * 256 + col0 + ci * 16 + c16] = acc[ri][ci][q] + bw[ci];
        }
      }
  } else {
    #pragma unroll
    for (int ri = 0; ri < 4; ++ri)
      #pragma unroll
      for (int q = 0; q < 4; ++q) {
        int rl = ri * 16 + kg * 4 + q;
        int rr = n0 + rl; int rc = rr < M ? rr : M - 1;
        float s = 0.f, s2 = 0.f;
        #pragma unroll
        for (int ci = 0; ci < 4; ++ci) {
          float r = res[(size_t)rc * 256 + col0 + ci * 16 + c16];
          float v = fmaxf(acc[ri][ci][q] + bw[ci] + r, 0.f);
          acc[ri][ci][q] = v;
          s += v; s2 += v * v;
        }
        #pragma unroll
        for (int m = 1; m < 16; m <<= 1) {
          s  += __shfl_xor(s, m);
          s2 += __shfl_xor(s2, m);
        }
        if (c16 == 0) {
          lnred[(rl * 4 + wv) * 2]     = s;
          lnred[(rl * 4 + wv) * 2 + 1] = s2;
        }
      }
    __syncthreads();
    #pragma unroll
    for (int ri = 0; ri < 4; ++ri)
      #pragma unroll
      for (int q = 0; q < 4; ++q) {
        int rl = ri * 16 + kg * 4 + q;
        float S = 0.f, S2 = 0.f;
        #pragma unroll
        for (int w = 0; w < 4; ++w) {
          S  += lnred[(rl * 4 + w) * 2];
          S2 += lnred[(rl * 4 + w) * 2 + 1];
        }
        float mean = S * (1.f / 256.f);
        float var = S2 * (1.f / 256.f) - mean * mean;
        float rstd = rsqrtf(var + 1e-5f);
        int row = n0 + rl;
        if (row < M) {
          #pragma unroll
          for (int ci = 0; ci < 4; ++ci)
            C[(size_t)row * 256 + col0 + ci * 16 + c16] =
                (acc[ri][ci][q] - mean) * rstd * lw[ci] + lb[ci];
        }
      }
  }
}

// ---------------- pooling (two-stage) + classifier ----------------
__global__ __launch_bounds__(256) void k_pool1(const float* __restrict__ h,
                                               const int* __restrict__ gstart,
                                               float* __restrict__ part) {
  int gi = blockIdx.x, ck = blockIdx.y;
  int c = (int)threadIdx.x;
  int s = gstart[gi], e = gstart[gi + 1], len = e - s;
  int cs = s + (int)(((long long)len * ck) >> 3);
  int ce = s + (int)(((long long)len * (ck + 1)) >> 3);
  float m = -3.402823466e+38f;
  int n = cs;
  for (; n + 2 <= ce; n += 2) {
    float x0 = h[(size_t)n * HID + c];
    float x1 = h[(size_t)(n + 1) * HID + c];
    m = fmaxf(m, fmaxf(x0, x1));
  }
  if (n < ce) m = fmaxf(m, h[(size_t)n * HID + c]);
  part[((size_t)gi * 8 + ck) * HID + c] = m;
}

__global__ __launch_bounds__(256) void k_pool2(const float* __restrict__ part,
                                               float* __restrict__ g) {
  int gi = blockIdx.x, c = (int)threadIdx.x;
  float m = part[((size_t)gi * 8) * HID + c];
  #pragma unroll
  for (int k = 1; k < 8; ++k) m = fmaxf(m, part[((size_t)gi * 8 + k) * HID + c]);
  g[gi * HID + c] = m;
}

__global__ __launch_bounds__(256) void k_classifier(const float* __restrict__ g,
                                                    const float* __restrict__ w1,
                                                    const float* __restrict__ b1,
                                                    const float* __restrict__ w2,
                                                    const float* __restrict__ b2,
                                                    float* __restrict__ out) {
  int gi = blockIdx.x, t = (int)threadIdx.x;
  __shared__ float gs[HID], zs[HID];
  gs[t] = g[gi * HID + t];
  __syncthreads();
  float s = b1[t];
  for (int k = 0; k < HID; ++k) s = fmaf(gs[k], w1[k * HID + t], s);
  zs[t] = fmaxf(s, 0.f);
  __syncthreads();
  if (t < 4) {
    float o = b2[t];
    for (int k = 0; k < HID; ++k) o = fmaf(zs[k], w2[k * 4 + t], o);
    out[gi * 4 + t] = o;
  }
}

// ---------------- launch ----------------
extern "C" void kernel_launch(void* const* d_in, const int* in_sizes, int n_in,
                              void* d_out, int out_size, void* d_ws, size_t ws_size,
                              hipStream_t stream) {
  const float* x      = (const float*)d_in[0];
  const int*   eidx   = (const int*)d_in[1];
  const int*   etype  = (const int*)d_in[2];
  const int*   batch  = (const int*)d_in[3];
  const float* in_w   = (const float*)d_in[4];
  const float* in_b   = (const float*)d_in[5];
  const float* root_w = (const float*)d_in[6];
  const float* rel_w  = (const float*)d_in[7];
  const float* conv_b = (const float*)d_in[8];
  const float* ln_w   = (const float*)d_in[9];
  const float* ln_b   = (const float*)d_in[10];
  const float* cls_w1 = (const float*)d_in[11];
  const float* cls_b1 = (const float*)d_in[12];
  const float* cls_w2 = (const float*)d_in[13];
  const float* cls_b2 = (const float*)d_in[14];
  float* out = (float*)d_out;

  char* ws = (char*)d_ws;
  size_t off = 0;
  auto alloc = [&](size_t bytes) -> void* {
    void* p = ws + off;
    off += (bytes + 255) & ~(size_t)255;
    return p;
  };
  float*    bufA      = (float*)alloc(sizeof(float) * (size_t)NN * HID);
  float*    bufB      = (float*)alloc(sizeof(float) * (size_t)NN * HID);
  float*    agg       = (float*)alloc(sizeof(float) * (size_t)NN * NREL * HID);
  unsigned* csr       = (unsigned*)alloc(sizeof(unsigned) * NE);
  int*      deg       = (int*)alloc(sizeof(int) * 53248);
  int*      row_start = (int*)alloc(sizeof(int) * (NN + 1));
  int*      cursor    = (int*)alloc(sizeof(int) * NN);
  int*      gstart    = (int*)alloc(sizeof(int) * (NG + 1));
  float*    gpool     = (float*)alloc(sizeof(float) * NG * HID);
  float*    gpart     = (float*)alloc(sizeof(float) * NG * 8 * HID);
  unsigned short* wInH = (unsigned short*)alloc(sizeof(unsigned short) * 96 * 256 * 8);
  unsigned short* wInL = (unsigned short*)alloc(sizeof(unsigned short) * 96 * 256 * 8);
  unsigned short* wLH[NLAY];
  unsigned short* wLL[NLAY];
  for (int L = 0; L < NLAY; ++L) {
    wLH[L] = (unsigned short*)alloc(sizeof(unsigned short) * 128 * 256 * 8);
    wLL[L] = (unsigned short*)alloc(sizeof(unsigned short) * 128 * 256 * 8);
  }
  (void)ws_size; (void)in_sizes; (void)n_in; (void)out_size;

  const int* esrc = eidx;
  const int* edst = eidx + NE;

  k_cvt<<<IND, 256, 0, stream>>>(in_w, IND, nullptr, IND, wInH, wInL);
  for (int L = 0; L < NLAY; ++L)
    k_cvt<<<HID + NREL * HID, 256, 0, stream>>>(
        root_w + (size_t)L * HID * HID, HID,
        rel_w + (size_t)L * NREL * HID * HID, HID + NREL * HID, wLH[L], wLL[L]);

  k_zero_int<<<(53248 + 255) / 256, 256, 0, stream>>>(deg, 53248);
  k_hist<<<(NE + 255) / 256, 256, 0, stream>>>(edst, deg);
  k_scan<<<1, 1024, 0, stream>>>(deg, row_start, cursor);
  k_scatter<<<(NE + 255) / 256, 256, 0, stream>>>(esrc, edst, etype, cursor, csr);
  k_graph_bounds<<<(NN + 255) / 256, 256, 0, stream>>>(batch, gstart);

  int gemm_grid = (NN + 63) / 64;   // 782
  k_gemm_mfma<0><<<gemm_grid, 256, 0, stream>>>(
      x, IND, nullptr, 0, IND, wInH, wInL, in_b,
      nullptr, nullptr, nullptr, bufA, NN, IND);

  float* hcur = bufA;
  float* hnext = bufB;
  for (int L = 0; L < NLAY; ++L) {
    k_aggregate<<<NN, 64, 0, stream>>>(hcur, row_start, csr, agg);
    k_gemm_mfma<1><<<gemm_grid, 256, 0, stream>>>(
        hcur, HID, agg, NREL * HID, HID, wLH[L], wLL[L],
        conv_b + L * HID, hcur, ln_w + L * HID, ln_b + L * HID,
        hnext, NN, HID + NREL * HID);
    float* tmp = hcur; hcur = hnext; hnext = tmp;
  }

  k_pool1<<<dim3(NG, 8), 256, 0, stream>>>(hcur, gstart, gpart);
  k_pool2<<<NG, 256, 0, stream>>>(gpart, gpool);
  k_classifier<<<NG, 256, 0, stream>>>(gpool, cls_w1, cls_b1, cls_w2, cls_b2, out);
}

// Round 9
// 1463.283 us; speedup vs baseline: 1.0654x; 1.0654x over previous
//
#include <hip/hip_runtime.h>
#include <cstdint>
#include <cstddef>

#define NN 50000
#define NE 800000
#define NG 64
#define IND 768
#define HID 256
#define NREL 3
#define NLAY 3

typedef __attribute__((ext_vector_type(4))) float f32x4;
typedef __attribute__((ext_vector_type(8))) short s16x8;
typedef __attribute__((ext_vector_type(4))) unsigned short u16x4;

// ---------------- utility ----------------
__global__ void k_zero_int(int* __restrict__ p, int n) {
  int i = blockIdx.x * 256 + threadIdx.x;
  if (i < n) p[i] = 0;
}

__global__ void k_hist(const int* __restrict__ dst, int* __restrict__ deg) {
  int e = blockIdx.x * 256 + threadIdx.x;
  if (e < NE) atomicAdd(&deg[dst[e]], 1);
}

__global__ __launch_bounds__(1024) void k_scan(const int* __restrict__ deg,
                                               int* __restrict__ row_start,
                                               int* __restrict__ cursor) {
  __shared__ int wsum[16];
  int t = threadIdx.x;
  int lane = t & 63, wid = t >> 6;
  int running = 0;
  if (t == 0) row_start[0] = 0;
  for (int base = 0; base < NN; base += 4096) {
    int idx = base + t * 4;
    int4 d = *(const int4*)(deg + idx);
    int s = d.x + d.y + d.z + d.w;
    int sc = s;
    #pragma unroll
    for (int off = 1; off < 64; off <<= 1) {
      int o = __shfl_up(sc, off);
      if (lane >= off) sc += o;
    }
    if (lane == 63) wsum[wid] = sc;
    __syncthreads();
    if (t == 0) {
      int a = 0;
      #pragma unroll
      for (int i = 0; i < 16; ++i) { a += wsum[i]; wsum[i] = a; }
    }
    __syncthreads();
    int woff = (wid == 0) ? 0 : wsum[wid - 1];
    int excl = running + woff + (sc - s);
    int e0 = excl, e1 = e0 + d.x, e2 = e1 + d.y, e3 = e2 + d.z, e4 = e3 + d.w;
    if (idx     < NN) { cursor[idx]     = e0; row_start[idx + 1] = e1; }
    if (idx + 1 < NN) { cursor[idx + 1] = e1; row_start[idx + 2] = e2; }
    if (idx + 2 < NN) { cursor[idx + 2] = e2; row_start[idx + 3] = e3; }
    if (idx + 3 < NN) { cursor[idx + 3] = e3; row_start[idx + 4] = e4; }
    running += wsum[15];
    __syncthreads();
  }
}

__global__ void k_scatter(const int* __restrict__ src, const int* __restrict__ dst,
                          const int* __restrict__ ety, int* __restrict__ cursor,
                          unsigned* __restrict__ csr) {
  int e = blockIdx.x * 256 + threadIdx.x;
  if (e >= NE) return;
  int pos = atomicAdd(&cursor[dst[e]], 1);
  csr[pos] = (unsigned)src[e] | ((unsigned)ety[e] << 16);
}

__global__ void k_graph_bounds(const int* __restrict__ batch, int* __restrict__ gstart) {
  int i = blockIdx.x * 256 + threadIdx.x;
  if (i >= NN) return;
  int b = batch[i];
  int bp = (i == 0) ? -1 : batch[i - 1];
  for (int g = bp + 1; g <= b; ++g) gstart[g] = i;
  if (i == NN - 1) {
    for (int g = b + 1; g <= NG; ++g) gstart[g] = NN;
  }
}

// ---------------- bf16 split helpers ----------------
__device__ __forceinline__ unsigned short bf16rne(float f) {
  union { float f; unsigned u; } x; x.f = f;
  unsigned r = (x.u + 0x7FFFu + ((x.u >> 16) & 1u)) >> 16;
  return (unsigned short)r;
}
__device__ __forceinline__ float bf2f(unsigned short h) {
  union { unsigned u; float f; } x; x.u = ((unsigned)h) << 16;
  return x.f;
}

// ---------------- aggregation ----------------
// one 64-thread block per node; thread t owns channels [4t,4t+4).
// Plain serial edge loop (R7's x4 unroll REGRESSED 180->242us: 4 concurrent
// 1KB gathers/wave at 82% occupancy thrash the 4MB per-XCD L2 - reverted).
// Output written as pre-split hi/lo bf16 planes (same bytes; split VALU is
// free here at ~10% VALUBusy) so the layer GEMM reads A2 fragments directly.
__global__ __launch_bounds__(64) void k_aggregate(const float* __restrict__ h,
                                                  const int* __restrict__ row_start,
                                                  const unsigned* __restrict__ csr,
                                                  unsigned short* __restrict__ aggH,
                                                  unsigned short* __restrict__ aggL) {
  int n = blockIdx.x;
  int t = threadIdx.x;
  int s = row_start[n], e = row_start[n + 1];
  float4 a0 = {0, 0, 0, 0}, a1 = {0, 0, 0, 0}, a2 = {0, 0, 0, 0};
  int c0 = 0, c1 = 0, c2 = 0;
  __shared__ unsigned buf[64];
  for (int base = s; base < e; base += 64) {
    int m = e - base; if (m > 64) m = 64;
    __syncthreads();
    if (t < m) buf[t] = csr[base + t];
    __syncthreads();
    for (int j = 0; j < m; ++j) {
      unsigned p = buf[j];
      int src = p & 0xFFFF;
      int ty = (int)(p >> 16);   // wave-uniform
      float4 v = *(const float4*)(h + (size_t)src * HID + t * 4);
      if (ty == 0)      { a0.x += v.x; a0.y += v.y; a0.z += v.z; a0.w += v.w; c0++; }
      else if (ty == 1) { a1.x += v.x; a1.y += v.y; a1.z += v.z; a1.w += v.w; c1++; }
      else              { a2.x += v.x; a2.y += v.y; a2.z += v.z; a2.w += v.w; c2++; }
    }
  }
  float i0 = 1.f / (float)(c0 > 1 ? c0 : 1);
  float i1 = 1.f / (float)(c1 > 1 ? c1 : 1);
  float i2 = 1.f / (float)(c2 > 1 ? c2 : 1);
  float vr[12] = {a0.x * i0, a0.y * i0, a0.z * i0, a0.w * i0,
                  a1.x * i1, a1.y * i1, a1.z * i1, a1.w * i1,
                  a2.x * i2, a2.y * i2, a2.z * i2, a2.w * i2};
  size_t ob = (size_t)n * (NREL * HID) + t * 4;
  #pragma unroll
  for (int r = 0; r < 3; ++r) {
    u16x4 hv, lv;
    #pragma unroll
    for (int j = 0; j < 4; ++j) {
      unsigned short hh = bf16rne(vr[r * 4 + j]);
      hv[j] = hh;
      lv[j] = bf16rne(vr[r * 4 + j] - bf2f(hh));
    }
    *(u16x4*)(aggH + ob + r * HID) = hv;
    *(u16x4*)(aggL + ob + r * HID) = lv;
  }
}

// weight convert: fp32 [Ktot][256] (two contiguous pieces) ->
// hi/lo bf16 packed [Ktot/8][256][8]  (linear for global_load_lds staging)
__global__ void k_cvt(const float* __restrict__ s1, int K1e,
                      const float* __restrict__ s2, int Ktot,
                      unsigned short* __restrict__ hi, unsigned short* __restrict__ lo) {
  int t = blockIdx.x * 256 + threadIdx.x;
  if (t >= Ktot * 256) return;
  int c = t & 255, k = t >> 8;
  float v = (k < K1e) ? s1[(size_t)k * 256 + c] : s2[(size_t)(k - K1e) * 256 + c];
  unsigned short h = bf16rne(v);
  unsigned short l = bf16rne(v - bf2f(h));
  size_t o = ((size_t)(k >> 3) * 256 + c) * 8 + (k & 7);
  hi[o] = h; lo[o] = l;
}

__device__ __forceinline__ void load_lds16b(const void* g, void* l) {
  __builtin_amdgcn_global_load_lds(
      (const __attribute__((address_space(1))) unsigned*)g,
      (__attribute__((address_space(3))) unsigned*)l, 16, 0, 0);
}

// ---------------- input-projection GEMM (fp32 A, 3-term bf16 split) ----------------
// R6/R7 structure: B via global_load_lds, A via LDS with distributed split.
// Epilogue writes C fp32 AND hi/lo bf16 planes (next kernel's A1 operand).
__global__ __launch_bounds__(256, 1) void k_gemm_in(
    const float* __restrict__ A1,
    const unsigned short* __restrict__ Bhi, const unsigned short* __restrict__ Blo,
    const float* __restrict__ bias,
    float* __restrict__ C, unsigned short* __restrict__ Ch, unsigned short* __restrict__ Cl,
    int M) {
  const int K = IND;
  __shared__ __align__(16) unsigned short AsH[4 * 64 * 8], AsL[4 * 64 * 8];
  __shared__ __align__(16) unsigned short BsH[4 * 256 * 8], BsL[4 * 256 * 8];
  int tid = (int)threadIdx.x;
  int lane = tid & 63, wv = tid >> 6;
  int n0 = (int)blockIdx.x * 64;
  int srow = tid >> 2, sg = tid & 3;
  int grow = n0 + srow; if (grow > M - 1) grow = M - 1;
  int c16 = lane & 15, kg = lane >> 4;
  int col0 = wv * 64;

  f32x4 acc[4][4] = {};
  int nkt = K / 32;

  float4 a0, a1;
  {
    const float* ap = A1 + (size_t)grow * IND + sg * 8;
    a0 = *(const float4*)ap;
    a1 = *(const float4*)(ap + 4);
  }

  for (int kt = 0; kt < nkt; ++kt) {
    __syncthreads();
    #pragma unroll
    for (int i = 0; i < 8; ++i) {
      int id = wv * 8 + i;
      const unsigned short* srcp = (id < 16) ? Bhi : Blo;
      unsigned short* dstp = (id < 16) ? BsH : BsL;
      int rem = id & 15, g = rem >> 2, ch = rem & 3;
      load_lds16b(srcp + (size_t)(kt * 4 + g) * 2048 + (ch * 64 + lane) * 8,
                  dstp + (g * 256 + ch * 64) * 8);
    }
    {
      float va[8] = {a0.x, a0.y, a0.z, a0.w, a1.x, a1.y, a1.z, a1.w};
      s16x8 hv, lv;
      #pragma unroll
      for (int j = 0; j < 8; ++j) {
        unsigned short h = bf16rne(va[j]);
        hv[j] = (short)h;
        lv[j] = (short)bf16rne(va[j] - bf2f(h));
      }
      int aoff = (sg * 64 + (srow ^ (sg << 2))) * 8;
      *(s16x8*)&AsH[aoff] = hv;
      *(s16x8*)&AsL[aoff] = lv;
    }
    __syncthreads();
    s16x8 ah[4], al[4];
    #pragma unroll
    for (int ri = 0; ri < 4; ++ri) {
      int ao = (kg * 64 + ((ri * 16 + c16) ^ (kg << 2))) * 8;
      ah[ri] = *(const s16x8*)&AsH[ao];
      al[ri] = *(const s16x8*)&AsL[ao];
    }
    int kn = (kt + 1) * 32;
    if (kn < K) {
      const float* ap = A1 + (size_t)grow * IND + kn + sg * 8;
      a0 = *(const float4*)ap;
      a1 = *(const float4*)(ap + 4);
    }
    #pragma unroll
    for (int ci = 0; ci < 4; ++ci) {
      int bo = (kg * 256 + col0 + ci * 16 + c16) * 8;
      s16x8 bh = *(const s16x8*)&BsH[bo];
      s16x8 bl = *(const s16x8*)&BsL[bo];
      #pragma unroll
      for (int ri = 0; ri < 4; ++ri) {
        acc[ri][ci] = __builtin_amdgcn_mfma_f32_16x16x32_bf16(ah[ri], bh, acc[ri][ci], 0, 0, 0);
        acc[ri][ci] = __builtin_amdgcn_mfma_f32_16x16x32_bf16(ah[ri], bl, acc[ri][ci], 0, 0, 0);
        acc[ri][ci] = __builtin_amdgcn_mfma_f32_16x16x32_bf16(al[ri], bh, acc[ri][ci], 0, 0, 0);
      }
    }
  }

  // epilogue: C fp32 + hi/lo planes. C/D layout: col=lane&15, row=(lane>>4)*4+reg
  float bw[4];
  #pragma unroll
  for (int ci = 0; ci < 4; ++ci) bw[ci] = bias[col0 + ci * 16 + c16];
  #pragma unroll
  for (int ri = 0; ri < 4; ++ri)
    #pragma unroll
    for (int q = 0; q < 4; ++q) {
      int row = n0 + ri * 16 + kg * 4 + q;
      if (row < M) {
        #pragma unroll
        for (int ci = 0; ci < 4; ++ci) {
          float v = acc[ri][ci][q] + bw[ci];
          size_t o = (size_t)row * 256 + col0 + ci * 16 + c16;
          C[o] = v;
          unsigned short hh = bf16rne(v);
          Ch[o] = hh;
          Cl[o] = bf16rne(v - bf2f(hh));
        }
      }
    }
}

// ---------------- layer GEMM: 1 barrier per K-tile ----------------
// A fragments loaded straight from pre-split global bf16 planes into regs
// (h planes lda=256, agg planes lda=768) -> no A LDS, no in-kernel split,
// no A barrier. B staged via global_load_lds into ping-pong LDS (2x32KB):
// tile kt reads buf[cur] while DMA fills buf[cur^1]; the single barrier's
// implicit vmcnt(0) drain publishes the DMA. 48 MFMA (~230cyc) vs 8
// ds_read_b128 (~96cyc) per tile -> MFMA critical path.
__global__ __launch_bounds__(256, 1) void k_gemm_L(
    const unsigned short* __restrict__ Ah1, const unsigned short* __restrict__ Al1,
    const unsigned short* __restrict__ Ah2, const unsigned short* __restrict__ Al2,
    const unsigned short* __restrict__ Bhi, const unsigned short* __restrict__ Blo,
    const float* __restrict__ bias, const float* __restrict__ res,
    const float* __restrict__ lnw, const float* __restrict__ lnb,
    float* __restrict__ C, unsigned short* __restrict__ Ch, unsigned short* __restrict__ Cl,
    int M) {
  const int K1 = HID, K = HID + NREL * HID;   // 256, 1024
  __shared__ __align__(16) unsigned short BsH[2][4 * 256 * 8];  // 16KB x2
  __shared__ __align__(16) unsigned short BsL[2][4 * 256 * 8];  // 16KB x2
  __shared__ float lnred[64 * 4 * 2];
  int tid = (int)threadIdx.x;
  int lane = tid & 63, wv = tid >> 6;
  int n0 = (int)blockIdx.x * 64;
  int c16 = lane & 15, kg = lane >> 4;
  int col0 = wv * 64;
  int arow[4];
  #pragma unroll
  for (int ri = 0; ri < 4; ++ri) {
    int r = n0 + ri * 16 + c16;
    arow[ri] = r < M ? r : M - 1;
  }

  f32x4 acc[4][4] = {};

  auto dmaB = [&](int kt, int b) {
    #pragma unroll
    for (int i = 0; i < 8; ++i) {
      int id = wv * 8 + i;
      const unsigned short* srcp = (id < 16) ? Bhi : Blo;
      unsigned short* dstp = (id < 16) ? &BsH[b][0] : &BsL[b][0];
      int rem = id & 15, g = rem >> 2, ch = rem & 3;
      load_lds16b(srcp + (size_t)(kt * 4 + g) * 2048 + (ch * 64 + lane) * 8,
                  dstp + (g * 256 + ch * 64) * 8);
    }
  };
  s16x8 ah[4], al[4], ahn[4] = {}, aln[4] = {};
  auto loadA = [&](int kt, s16x8* AH, s16x8* AL) {
    int kk = kt * 32;
    const unsigned short *ph, *pl; int ld, kc;
    if (kk < K1) { ph = Ah1; pl = Al1; ld = HID; kc = kk; }
    else         { ph = Ah2; pl = Al2; ld = NREL * HID; kc = kk - K1; }
    #pragma unroll
    for (int ri = 0; ri < 4; ++ri) {
      size_t o = (size_t)arow[ri] * ld + kc + kg * 8;
      AH[ri] = *(const s16x8*)(ph + o);
      AL[ri] = *(const s16x8*)(pl + o);
    }
  };

  dmaB(0, 0);
  loadA(0, ah, al);
  int cur = 0;
  const int nkt = K / 32;   // 32
  for (int kt = 0; kt < nkt; ++kt) {
    __syncthreads();   // buf[cur] DMA published; prior tile's reads done
    if (kt + 1 < nkt) {
      dmaB(kt + 1, cur ^ 1);
      loadA(kt + 1, ahn, aln);
    }
    #pragma unroll
    for (int ci = 0; ci < 4; ++ci) {
      int bo = (kg * 256 + col0 + ci * 16 + c16) * 8;
      s16x8 bh = *(const s16x8*)&BsH[cur][bo];
      s16x8 bl = *(const s16x8*)&BsL[cur][bo];
      #pragma unroll
      for (int ri = 0; ri < 4; ++ri) {
        acc[ri][ci] = __builtin_amdgcn_mfma_f32_16x16x32_bf16(ah[ri], bh, acc[ri][ci], 0, 0, 0);
        acc[ri][ci] = __builtin_amdgcn_mfma_f32_16x16x32_bf16(ah[ri], bl, acc[ri][ci], 0, 0, 0);
        acc[ri][ci] = __builtin_amdgcn_mfma_f32_16x16x32_bf16(al[ri], bh, acc[ri][ci], 0, 0, 0);
      }
    }
    #pragma unroll
    for (int ri = 0; ri < 4; ++ri) { ah[ri] = ahn[ri]; al[ri] = aln[ri]; }
    cur ^= 1;
  }

  // ---------------- epilogue: +bias +res, relu, LN, write fp32 + planes ----------------
  float bw[4], lw[4], lb[4];
  #pragma unroll
  for (int ci = 0; ci < 4; ++ci) {
    int col = col0 + ci * 16 + c16;
    bw[ci] = bias[col];
    lw[ci] = lnw[col];
    lb[ci] = lnb[col];
  }
  #pragma unroll
  for (int ri = 0; ri < 4; ++ri)
    #pragma unroll
    for (int q = 0; q < 4; ++q) {
      int rl = ri * 16 + kg * 4 + q;
      int rr = n0 + rl; int rc = rr < M ? rr : M - 1;
      float s = 0.f, s2 = 0.f;
      #pragma unroll
      for (int ci = 0; ci < 4; ++ci) {
        float r = res[(size_t)rc * 256 + col0 + ci * 16 + c16];
        float v = fmaxf(acc[ri][ci][q] + bw[ci] + r, 0.f);
        acc[ri][ci][q] = v;
        s += v; s2 += v * v;
      }
      #pragma unroll
      for (int m = 1; m < 16; m <<= 1) {
        s  += __shfl_xor(s, m);
        s2 += __shfl_xor(s2, m);
      }
      if (c16 == 0) {
        lnred[(rl * 4 + wv) * 2]     = s;
        lnred[(rl * 4 + wv) * 2 + 1] = s2;
      }
    }
  __syncthreads();
  #pragma unroll
  for (int ri = 0; ri < 4; ++ri)
    #pragma unroll
    for (int q = 0; q < 4; ++q) {
      int rl = ri * 16 + kg * 4 + q;
      float S = 0.f, S2 = 0.f;
      #pragma unroll
      for (int w = 0; w < 4; ++w) {
        S  += lnred[(rl * 4 + w) * 2];
        S2 += lnred[(rl * 4 + w) * 2 + 1];
      }
      float mean = S * (1.f / 256.f);
      float var = S2 * (1.f / 256.f) - mean * mean;
      float rstd = rsqrtf(var + 1e-5f);
      int row = n0 + rl;
      if (row < M) {
        #pragma unroll
        for (int ci = 0; ci < 4; ++ci) {
          float v = (acc[ri][ci][q] - mean) * rstd * lw[ci] + lb[ci];
          size_t o = (size_t)row * 256 + col0 + ci * 16 + c16;
          C[o] = v;
          unsigned short hh = bf16rne(v);
          Ch[o] = hh;
          Cl[o] = bf16rne(v - bf2f(hh));
        }
      }
    }
}

// ---------------- pooling (two-stage) + classifier ----------------
__global__ __launch_bounds__(256) void k_pool1(const float* __restrict__ h,
                                               const int* __restrict__ gstart,
                                               float* __restrict__ part) {
  int gi = blockIdx.x, ck = blockIdx.y;
  int c = (int)threadIdx.x;
  int s = gstart[gi], e = gstart[gi + 1], len = e - s;
  int cs = s + (int)(((long long)len * ck) >> 3);
  int ce = s + (int)(((long long)len * (ck + 1)) >> 3);
  float m = -3.402823466e+38f;
  int n = cs;
  for (; n + 2 <= ce; n += 2) {
    float x0 = h[(size_t)n * HID + c];
    float x1 = h[(size_t)(n + 1) * HID + c];
    m = fmaxf(m, fmaxf(x0, x1));
  }
  if (n < ce) m = fmaxf(m, h[(size_t)n * HID + c]);
  part[((size_t)gi * 8 + ck) * HID + c] = m;
}

__global__ __launch_bounds__(256) void k_pool2(const float* __restrict__ part,
                                               float* __restrict__ g) {
  int gi = blockIdx.x, c = (int)threadIdx.x;
  float m = part[((size_t)gi * 8) * HID + c];
  #pragma unroll
  for (int k = 1; k < 8; ++k) m = fmaxf(m, part[((size_t)gi * 8 + k) * HID + c]);
  g[gi * HID + c] = m;
}

__global__ __launch_bounds__(256) void k_classifier(const float* __restrict__ g,
                                                    const float* __restrict__ w1,
                                                    const float* __restrict__ b1,
                                                    const float* __restrict__ w2,
                                                    const float* __restrict__ b2,
                                                    float* __restrict__ out) {
  int gi = blockIdx.x, t = (int)threadIdx.x;
  __shared__ float gs[HID], zs[HID];
  gs[t] = g[gi * HID + t];
  __syncthreads();
  float s = b1[t];
  for (int k = 0; k < HID; ++k) s = fmaf(gs[k], w1[k * HID + t], s);
  zs[t] = fmaxf(s, 0.f);
  __syncthreads();
  if (t < 4) {
    float o = b2[t];
    for (int k = 0; k < HID; ++k) o = fmaf(zs[k], w2[k * 4 + t], o);
    out[gi * 4 + t] = o;
  }
}

// ---------------- launch ----------------
extern "C" void kernel_launch(void* const* d_in, const int* in_sizes, int n_in,
                              void* d_out, int out_size, void* d_ws, size_t ws_size,
                              hipStream_t stream) {
  const float* x      = (const float*)d_in[0];
  const int*   eidx   = (const int*)d_in[1];
  const int*   etype  = (const int*)d_in[2];
  const int*   batch  = (const int*)d_in[3];
  const float* in_w   = (const float*)d_in[4];
  const float* in_b   = (const float*)d_in[5];
  const float* root_w = (const float*)d_in[6];
  const float* rel_w  = (const float*)d_in[7];
  const float* conv_b = (const float*)d_in[8];
  const float* ln_w   = (const float*)d_in[9];
  const float* ln_b   = (const float*)d_in[10];
  const float* cls_w1 = (const float*)d_in[11];
  const float* cls_b1 = (const float*)d_in[12];
  const float* cls_w2 = (const float*)d_in[13];
  const float* cls_b2 = (const float*)d_in[14];
  float* out = (float*)d_out;

  char* ws = (char*)d_ws;
  size_t off = 0;
  auto alloc = [&](size_t bytes) -> void* {
    void* p = ws + off;
    off += (bytes + 255) & ~(size_t)255;
    return p;
  };
  float*    bufA   = (float*)alloc(sizeof(float) * (size_t)NN * HID);
  float*    bufB   = (float*)alloc(sizeof(float) * (size_t)NN * HID);
  unsigned short* hAh = (unsigned short*)alloc(sizeof(unsigned short) * (size_t)NN * HID);
  unsigned short* hAl = (unsigned short*)alloc(sizeof(unsigned short) * (size_t)NN * HID);
  unsigned short* hBh = (unsigned short*)alloc(sizeof(unsigned short) * (size_t)NN * HID);
  unsigned short* hBl = (unsigned short*)alloc(sizeof(unsigned short) * (size_t)NN * HID);
  unsigned short* aggH = (unsigned short*)alloc(sizeof(unsigned short) * (size_t)NN * NREL * HID);
  unsigned short* aggL = (unsigned short*)alloc(sizeof(unsigned short) * (size_t)NN * NREL * HID);
  unsigned* csr       = (unsigned*)alloc(sizeof(unsigned) * NE);
  int*      deg       = (int*)alloc(sizeof(int) * 53248);
  int*      row_start = (int*)alloc(sizeof(int) * (NN + 1));
  int*      cursor    = (int*)alloc(sizeof(int) * NN);
  int*      gstart    = (int*)alloc(sizeof(int) * (NG + 1));
  float*    gpool     = (float*)alloc(sizeof(float) * NG * HID);
  float*    gpart     = (float*)alloc(sizeof(float) * NG * 8 * HID);
  unsigned short* wInH = (unsigned short*)alloc(sizeof(unsigned short) * 96 * 256 * 8);
  unsigned short* wInL = (unsigned short*)alloc(sizeof(unsigned short) * 96 * 256 * 8);
  unsigned short* wLH[NLAY];
  unsigned short* wLL[NLAY];
  for (int L = 0; L < NLAY; ++L) {
    wLH[L] = (unsigned short*)alloc(sizeof(unsigned short) * 128 * 256 * 8);
    wLL[L] = (unsigned short*)alloc(sizeof(unsigned short) * 128 * 256 * 8);
  }
  (void)ws_size; (void)in_sizes; (void)n_in; (void)out_size;

  const int* esrc = eidx;
  const int* edst = eidx + NE;

  k_cvt<<<IND, 256, 0, stream>>>(in_w, IND, nullptr, IND, wInH, wInL);
  for (int L = 0; L < NLAY; ++L)
    k_cvt<<<HID + NREL * HID, 256, 0, stream>>>(
        root_w + (size_t)L * HID * HID, HID,
        rel_w + (size_t)L * NREL * HID * HID, HID + NREL * HID, wLH[L], wLL[L]);

  k_zero_int<<<(53248 + 255) / 256, 256, 0, stream>>>(deg, 53248);
  k_hist<<<(NE + 255) / 256, 256, 0, stream>>>(edst, deg);
  k_scan<<<1, 1024, 0, stream>>>(deg, row_start, cursor);
  k_scatter<<<(NE + 255) / 256, 256, 0, stream>>>(esrc, edst, etype, cursor, csr);
  k_graph_bounds<<<(NN + 255) / 256, 256, 0, stream>>>(batch, gstart);

  int gemm_grid = (NN + 63) / 64;   // 782
  k_gemm_in<<<gemm_grid, 256, 0, stream>>>(x, wInH, wInL, in_b, bufA, hAh, hAl, NN);

  float* hcur = bufA;  unsigned short* hch = hAh;  unsigned short* hcl = hAl;
  float* hnxt = bufB;  unsigned short* hnh = hBh;  unsigned short* hnl = hBl;
  for (int L = 0; L < NLAY; ++L) {
    k_aggregate<<<NN, 64, 0, stream>>>(hcur, row_start, csr, aggH, aggL);
    k_gemm_L<<<gemm_grid, 256, 0, stream>>>(
        hch, hcl, aggH, aggL, wLH[L], wLL[L],
        conv_b + L * HID, hcur, ln_w + L * HID, ln_b + L * HID,
        hnxt, hnh, hnl, NN);
    float* tf = hcur; hcur = hnxt; hnxt = tf;
    unsigned short* th = hch; hch = hnh; hnh = th;
    unsigned short* tl = hcl; hcl = hnl; hnl = tl;
  }

  k_pool1<<<dim3(NG, 8), 256, 0, stream>>>(hcur, gstart, gpart);
  k_pool2<<<NG, 256, 0, stream>>>(gpart, gpool);
  k_classifier<<<NG, 256, 0, stream>>>(gpool, cls_w1, cls_b1, cls_w2, cls_b2, out);
}

// Round 10
// 1301.395 us; speedup vs baseline: 1.1979x; 1.1244x over previous
//
#include <hip/hip_runtime.h>
#include <cstdint>
#include <cstddef>

#define NN 50000
#define NE 800000
#define NG 64
#define IND 768
#define HID 256
#define NREL 3
#define NLAY 3

typedef __attribute__((ext_vector_type(4))) float f32x4;
typedef __attribute__((ext_vector_type(8))) short s16x8;
typedef __attribute__((ext_vector_type(4))) unsigned short u16x4;

// ---------------- utility ----------------
__global__ void k_zero_int(int* __restrict__ p, int n) {
  int i = blockIdx.x * 256 + threadIdx.x;
  if (i < n) p[i] = 0;
}

__global__ void k_hist(const int* __restrict__ dst, int* __restrict__ deg) {
  int e = blockIdx.x * 256 + threadIdx.x;
  if (e < NE) atomicAdd(&deg[dst[e]], 1);
}

__global__ __launch_bounds__(1024) void k_scan(const int* __restrict__ deg,
                                               int* __restrict__ row_start,
                                               int* __restrict__ cursor) {
  __shared__ int wsum[16];
  int t = threadIdx.x;
  int lane = t & 63, wid = t >> 6;
  int running = 0;
  if (t == 0) row_start[0] = 0;
  for (int base = 0; base < NN; base += 4096) {
    int idx = base + t * 4;
    int4 d = *(const int4*)(deg + idx);
    int s = d.x + d.y + d.z + d.w;
    int sc = s;
    #pragma unroll
    for (int off = 1; off < 64; off <<= 1) {
      int o = __shfl_up(sc, off);
      if (lane >= off) sc += o;
    }
    if (lane == 63) wsum[wid] = sc;
    __syncthreads();
    if (t == 0) {
      int a = 0;
      #pragma unroll
      for (int i = 0; i < 16; ++i) { a += wsum[i]; wsum[i] = a; }
    }
    __syncthreads();
    int woff = (wid == 0) ? 0 : wsum[wid - 1];
    int excl = running + woff + (sc - s);
    int e0 = excl, e1 = e0 + d.x, e2 = e1 + d.y, e3 = e2 + d.z, e4 = e3 + d.w;
    if (idx     < NN) { cursor[idx]     = e0; row_start[idx + 1] = e1; }
    if (idx + 1 < NN) { cursor[idx + 1] = e1; row_start[idx + 2] = e2; }
    if (idx + 2 < NN) { cursor[idx + 2] = e2; row_start[idx + 3] = e3; }
    if (idx + 3 < NN) { cursor[idx + 3] = e3; row_start[idx + 4] = e4; }
    running += wsum[15];
    __syncthreads();
  }
}

__global__ void k_scatter(const int* __restrict__ src, const int* __restrict__ dst,
                          const int* __restrict__ ety, int* __restrict__ cursor,
                          unsigned* __restrict__ csr) {
  int e = blockIdx.x * 256 + threadIdx.x;
  if (e >= NE) return;
  int pos = atomicAdd(&cursor[dst[e]], 1);
  csr[pos] = (unsigned)src[e] | ((unsigned)ety[e] << 16);
}

__global__ void k_graph_bounds(const int* __restrict__ batch, int* __restrict__ gstart) {
  int i = blockIdx.x * 256 + threadIdx.x;
  if (i >= NN) return;
  int b = batch[i];
  int bp = (i == 0) ? -1 : batch[i - 1];
  for (int g = bp + 1; g <= b; ++g) gstart[g] = i;
  if (i == NN - 1) {
    for (int g = b + 1; g <= NG; ++g) gstart[g] = NN;
  }
}

// ---------------- bf16 split helpers ----------------
__device__ __forceinline__ unsigned short bf16rne(float f) {
  union { float f; unsigned u; } x; x.f = f;
  unsigned r = (x.u + 0x7FFFu + ((x.u >> 16) & 1u)) >> 16;
  return (unsigned short)r;
}
__device__ __forceinline__ float bf2f(unsigned short h) {
  union { unsigned u; float f; } x; x.u = ((unsigned)h) << 16;
  return x.f;
}

// ---------------- aggregation ----------------
// one 64-thread block per node; thread t owns channels [4t,4t+4).
// Plain serial edge loop (x4 unroll regressed: L2 thrash). Output written as
// pre-split hi/lo bf16 planes so the layer GEMM DMAs A fragments directly.
__global__ __launch_bounds__(64) void k_aggregate(const float* __restrict__ h,
                                                  const int* __restrict__ row_start,
                                                  const unsigned* __restrict__ csr,
                                                  unsigned short* __restrict__ aggH,
                                                  unsigned short* __restrict__ aggL) {
  int n = blockIdx.x;
  int t = threadIdx.x;
  int s = row_start[n], e = row_start[n + 1];
  float4 a0 = {0, 0, 0, 0}, a1 = {0, 0, 0, 0}, a2 = {0, 0, 0, 0};
  int c0 = 0, c1 = 0, c2 = 0;
  __shared__ unsigned buf[64];
  for (int base = s; base < e; base += 64) {
    int m = e - base; if (m > 64) m = 64;
    __syncthreads();
    if (t < m) buf[t] = csr[base + t];
    __syncthreads();
    for (int j = 0; j < m; ++j) {
      unsigned p = buf[j];
      int src = p & 0xFFFF;
      int ty = (int)(p >> 16);   // wave-uniform
      float4 v = *(const float4*)(h + (size_t)src * HID + t * 4);
      if (ty == 0)      { a0.x += v.x; a0.y += v.y; a0.z += v.z; a0.w += v.w; c0++; }
      else if (ty == 1) { a1.x += v.x; a1.y += v.y; a1.z += v.z; a1.w += v.w; c1++; }
      else              { a2.x += v.x; a2.y += v.y; a2.z += v.z; a2.w += v.w; c2++; }
    }
  }
  float i0 = 1.f / (float)(c0 > 1 ? c0 : 1);
  float i1 = 1.f / (float)(c1 > 1 ? c1 : 1);
  float i2 = 1.f / (float)(c2 > 1 ? c2 : 1);
  float vr[12] = {a0.x * i0, a0.y * i0, a0.z * i0, a0.w * i0,
                  a1.x * i1, a1.y * i1, a1.z * i1, a1.w * i1,
                  a2.x * i2, a2.y * i2, a2.z * i2, a2.w * i2};
  size_t ob = (size_t)n * (NREL * HID) + t * 4;
  #pragma unroll
  for (int r = 0; r < 3; ++r) {
    u16x4 hv, lv;
    #pragma unroll
    for (int j = 0; j < 4; ++j) {
      unsigned short hh = bf16rne(vr[r * 4 + j]);
      hv[j] = hh;
      lv[j] = bf16rne(vr[r * 4 + j] - bf2f(hh));
    }
    *(u16x4*)(aggH + ob + r * HID) = hv;
    *(u16x4*)(aggL + ob + r * HID) = lv;
  }
}

// weight convert: fp32 [Ktot][256] (two contiguous pieces) ->
// hi/lo bf16 packed [Ktot/8][256][8]  (linear for global_load_lds staging)
__global__ void k_cvt(const float* __restrict__ s1, int K1e,
                      const float* __restrict__ s2, int Ktot,
                      unsigned short* __restrict__ hi, unsigned short* __restrict__ lo) {
  int t = blockIdx.x * 256 + threadIdx.x;
  if (t >= Ktot * 256) return;
  int c = t & 255, k = t >> 8;
  float v = (k < K1e) ? s1[(size_t)k * 256 + c] : s2[(size_t)(k - K1e) * 256 + c];
  unsigned short h = bf16rne(v);
  unsigned short l = bf16rne(v - bf2f(h));
  size_t o = ((size_t)(k >> 3) * 256 + c) * 8 + (k & 7);
  hi[o] = h; lo[o] = l;
}

__device__ __forceinline__ void load_lds16b(const void* g, void* l) {
  __builtin_amdgcn_global_load_lds(
      (const __attribute__((address_space(1))) unsigned*)g,
      (__attribute__((address_space(3))) unsigned*)l, 16, 0, 0);
}

// ---------------- input-projection GEMM (fp32 A, 3-term bf16 split) ----------------
// R6 structure: B via global_load_lds, A via LDS with distributed in-kernel split.
// Epilogue writes C fp32 AND hi/lo bf16 planes (next kernel's A1 operand).
__global__ __launch_bounds__(256, 1) void k_gemm_in(
    const float* __restrict__ A1,
    const unsigned short* __restrict__ Bhi, const unsigned short* __restrict__ Blo,
    const float* __restrict__ bias,
    float* __restrict__ C, unsigned short* __restrict__ Ch, unsigned short* __restrict__ Cl,
    int M) {
  const int K = IND;
  __shared__ __align__(16) unsigned short AsH[4 * 64 * 8], AsL[4 * 64 * 8];
  __shared__ __align__(16) unsigned short BsH[4 * 256 * 8], BsL[4 * 256 * 8];
  int tid = (int)threadIdx.x;
  int lane = tid & 63, wv = tid >> 6;
  int n0 = (int)blockIdx.x * 64;
  int srow = tid >> 2, sg = tid & 3;
  int grow = n0 + srow; if (grow > M - 1) grow = M - 1;
  int c16 = lane & 15, kg = lane >> 4;
  int col0 = wv * 64;

  f32x4 acc[4][4] = {};
  int nkt = K / 32;

  float4 a0, a1;
  {
    const float* ap = A1 + (size_t)grow * IND + sg * 8;
    a0 = *(const float4*)ap;
    a1 = *(const float4*)(ap + 4);
  }

  for (int kt = 0; kt < nkt; ++kt) {
    __syncthreads();
    #pragma unroll
    for (int i = 0; i < 8; ++i) {
      int id = wv * 8 + i;
      const unsigned short* srcp = (id < 16) ? Bhi : Blo;
      unsigned short* dstp = (id < 16) ? BsH : BsL;
      int rem = id & 15, g = rem >> 2, ch = rem & 3;
      load_lds16b(srcp + (size_t)(kt * 4 + g) * 2048 + (ch * 64 + lane) * 8,
                  dstp + (g * 256 + ch * 64) * 8);
    }
    {
      float va[8] = {a0.x, a0.y, a0.z, a0.w, a1.x, a1.y, a1.z, a1.w};
      s16x8 hv, lv;
      #pragma unroll
      for (int j = 0; j < 8; ++j) {
        unsigned short h = bf16rne(va[j]);
        hv[j] = (short)h;
        lv[j] = (short)bf16rne(va[j] - bf2f(h));
      }
      int aoff = (sg * 64 + (srow ^ (sg << 2))) * 8;
      *(s16x8*)&AsH[aoff] = hv;
      *(s16x8*)&AsL[aoff] = lv;
    }
    __syncthreads();
    s16x8 ah[4], al[4];
    #pragma unroll
    for (int ri = 0; ri < 4; ++ri) {
      int ao = (kg * 64 + ((ri * 16 + c16) ^ (kg << 2))) * 8;
      ah[ri] = *(const s16x8*)&AsH[ao];
      al[ri] = *(const s16x8*)&AsL[ao];
    }
    int kn = (kt + 1) * 32;
    if (kn < K) {
      const float* ap = A1 + (size_t)grow * IND + kn + sg * 8;
      a0 = *(const float4*)ap;
      a1 = *(const float4*)(ap + 4);
    }
    #pragma unroll
    for (int ci = 0; ci < 4; ++ci) {
      int bo = (kg * 256 + col0 + ci * 16 + c16) * 8;
      s16x8 bh = *(const s16x8*)&BsH[bo];
      s16x8 bl = *(const s16x8*)&BsL[bo];
      #pragma unroll
      for (int ri = 0; ri < 4; ++ri) {
        acc[ri][ci] = __builtin_amdgcn_mfma_f32_16x16x32_bf16(ah[ri], bh, acc[ri][ci], 0, 0, 0);
        acc[ri][ci] = __builtin_amdgcn_mfma_f32_16x16x32_bf16(ah[ri], bl, acc[ri][ci], 0, 0, 0);
        acc[ri][ci] = __builtin_amdgcn_mfma_f32_16x16x32_bf16(al[ri], bh, acc[ri][ci], 0, 0, 0);
      }
    }
  }

  // epilogue: C fp32 + hi/lo planes. C/D layout: col=lane&15, row=(lane>>4)*4+reg
  float bw[4];
  #pragma unroll
  for (int ci = 0; ci < 4; ++ci) bw[ci] = bias[col0 + ci * 16 + c16];
  #pragma unroll
  for (int ri = 0; ri < 4; ++ri)
    #pragma unroll
    for (int q = 0; q < 4; ++q) {
      int row = n0 + ri * 16 + kg * 4 + q;
      if (row < M) {
        #pragma unroll
        for (int ci = 0; ci < 4; ++ci) {
          float v = acc[ri][ci][q] + bw[ci];
          size_t o = (size_t)row * 256 + col0 + ci * 16 + c16;
          C[o] = v;
          unsigned short hh = bf16rne(v);
          Ch[o] = hh;
          Cl[o] = bf16rne(v - bf2f(hh));
        }
      }
    }
}

// ---------------- layer GEMM: R6 2-barrier structure, A AND B via DMA ----------------
// R9 post-mortem: 1-barrier + per-lane A register-gather REGRESSED (149->215us):
// the A gather is 16 scattered cache-lines/instr and the single barrier's
// vmcnt(0) drain serializes it; 66KB LDS halved occupancy. This version stages
// A from the pre-split global planes via contiguous global_load_lds (2 instrs/
// wave/tile, 1KB each) into AsH/AsL [kg][64][8] - no split VALU, no gather.
// lnred aliases AsH after the K-loop: LDS = 40960B exactly -> 4 blocks/CU.
__global__ __launch_bounds__(256, 1) void k_gemm_L(
    const unsigned short* __restrict__ Ah1, const unsigned short* __restrict__ Al1,
    const unsigned short* __restrict__ Ah2, const unsigned short* __restrict__ Al2,
    const unsigned short* __restrict__ Bhi, const unsigned short* __restrict__ Blo,
    const float* __restrict__ bias, const float* __restrict__ res,
    const float* __restrict__ lnw, const float* __restrict__ lnb,
    float* __restrict__ C, unsigned short* __restrict__ Ch, unsigned short* __restrict__ Cl,
    int M) {
  const int K1 = HID, K = HID + NREL * HID;   // 256, 1024
  __shared__ __align__(16) unsigned short AsH[4 * 64 * 8], AsL[4 * 64 * 8];   // 4KB each
  __shared__ __align__(16) unsigned short BsH[4 * 256 * 8], BsL[4 * 256 * 8]; // 16KB each
  int tid = (int)threadIdx.x;
  int lane = tid & 63, wv = tid >> 6;
  int n0 = (int)blockIdx.x * 64;
  int c16 = lane & 15, kg = lane >> 4;
  int col0 = wv * 64;
  int alane = n0 + lane; if (alane > M - 1) alane = M - 1;  // A-DMA source row

  f32x4 acc[4][4] = {};
  const int nkt = K / 32;   // 32

  for (int kt = 0; kt < nkt; ++kt) {
    int kk = kt * 32;
    __syncthreads();   // prior tile's frag reads complete
    // B: 8 DMA instrs/wave, contiguous 1KB each
    #pragma unroll
    for (int i = 0; i < 8; ++i) {
      int id = wv * 8 + i;
      const unsigned short* srcp = (id < 16) ? Bhi : Blo;
      unsigned short* dstp = (id < 16) ? BsH : BsL;
      int rem = id & 15, g = rem >> 2, ch = rem & 3;
      load_lds16b(srcp + (size_t)(kt * 4 + g) * 2048 + (ch * 64 + lane) * 8,
                  dstp + (g * 256 + ch * 64) * 8);
    }
    // A: 2 DMA instrs/wave (8 total: hi g0..3, lo g0..3), contiguous 1KB each
    {
      const unsigned short *ph, *pl; int ld, kc;
      if (kk < K1) { ph = Ah1; pl = Al1; ld = HID; kc = kk; }
      else         { ph = Ah2; pl = Al2; ld = NREL * HID; kc = kk - K1; }
      #pragma unroll
      for (int i = 0; i < 2; ++i) {
        int id = wv * 2 + i;        // 0..7
        int g = id & 3;
        const unsigned short* srcp = (id < 4) ? ph : pl;
        unsigned short* dstp = (id < 4) ? AsH : AsL;
        load_lds16b(srcp + (size_t)alane * ld + kc + g * 8, dstp + g * 64 * 8);
      }
    }
    __syncthreads();   // vmcnt drained: As and Bs resident
    s16x8 ah[4], al[4];
    #pragma unroll
    for (int ri = 0; ri < 4; ++ri) {
      int ao = (kg * 64 + ri * 16 + c16) * 8;
      ah[ri] = *(const s16x8*)&AsH[ao];
      al[ri] = *(const s16x8*)&AsL[ao];
    }
    #pragma unroll
    for (int ci = 0; ci < 4; ++ci) {
      int bo = (kg * 256 + col0 + ci * 16 + c16) * 8;
      s16x8 bh = *(const s16x8*)&BsH[bo];
      s16x8 bl = *(const s16x8*)&BsL[bo];
      #pragma unroll
      for (int ri = 0; ri < 4; ++ri) {
        acc[ri][ci] = __builtin_amdgcn_mfma_f32_16x16x32_bf16(ah[ri], bh, acc[ri][ci], 0, 0, 0);
        acc[ri][ci] = __builtin_amdgcn_mfma_f32_16x16x32_bf16(ah[ri], bl, acc[ri][ci], 0, 0, 0);
        acc[ri][ci] = __builtin_amdgcn_mfma_f32_16x16x32_bf16(al[ri], bh, acc[ri][ci], 0, 0, 0);
      }
    }
  }

  // ---------------- epilogue: +bias +res, relu, LN, write fp32 + planes ----------------
  __syncthreads();                    // all frag reads done -> safe to alias AsH
  float* lnred = (float*)AsH;         // 2KB reuse (64 rows x 4 waves x 2)
  float bw[4], lw[4], lb[4];
  #pragma unroll
  for (int ci = 0; ci < 4; ++ci) {
    int col = col0 + ci * 16 + c16;
    bw[ci] = bias[col];
    lw[ci] = lnw[col];
    lb[ci] = lnb[col];
  }
  #pragma unroll
  for (int ri = 0; ri < 4; ++ri)
    #pragma unroll
    for (int q = 0; q < 4; ++q) {
      int rl = ri * 16 + kg * 4 + q;
      int rr = n0 + rl; int rc = rr < M ? rr : M - 1;
      float s = 0.f, s2 = 0.f;
      #pragma unroll
      for (int ci = 0; ci < 4; ++ci) {
        float r = res[(size_t)rc * 256 + col0 + ci * 16 + c16];
        float v = fmaxf(acc[ri][ci][q] + bw[ci] + r, 0.f);
        acc[ri][ci][q] = v;
        s += v; s2 += v * v;
      }
      #pragma unroll
      for (int m = 1; m < 16; m <<= 1) {
        s  += __shfl_xor(s, m);
        s2 += __shfl_xor(s2, m);
      }
      if (c16 == 0) {
        lnred[(rl * 4 + wv) * 2]     = s;
        lnred[(rl * 4 + wv) * 2 + 1] = s2;
      }
    }
  __syncthreads();
  #pragma unroll
  for (int ri = 0; ri < 4; ++ri)
    #pragma unroll
    for (int q = 0; q < 4; ++q) {
      int rl = ri * 16 + kg * 4 + q;
      float S = 0.f, S2 = 0.f;
      #pragma unroll
      for (int w = 0; w < 4; ++w) {
        S  += lnred[(rl * 4 + w) * 2];
        S2 += lnred[(rl * 4 + w) * 2 + 1];
      }
      float mean = S * (1.f / 256.f);
      float var = S2 * (1.f / 256.f) - mean * mean;
      float rstd = rsqrtf(var + 1e-5f);
      int row = n0 + rl;
      if (row < M) {
        #pragma unroll
        for (int ci = 0; ci < 4; ++ci) {
          float v = (acc[ri][ci][q] - mean) * rstd * lw[ci] + lb[ci];
          size_t o = (size_t)row * 256 + col0 + ci * 16 + c16;
          C[o] = v;
          unsigned short hh = bf16rne(v);
          Ch[o] = hh;
          Cl[o] = bf16rne(v - bf2f(hh));
        }
      }
    }
}

// ---------------- pooling (two-stage) + classifier ----------------
__global__ __launch_bounds__(256) void k_pool1(const float* __restrict__ h,
                                               const int* __restrict__ gstart,
                                               float* __restrict__ part) {
  int gi = blockIdx.x, ck = blockIdx.y;
  int c = (int)threadIdx.x;
  int s = gstart[gi], e = gstart[gi + 1], len = e - s;
  int cs = s + (int)(((long long)len * ck) >> 3);
  int ce = s + (int)(((long long)len * (ck + 1)) >> 3);
  float m = -3.402823466e+38f;
  int n = cs;
  for (; n + 2 <= ce; n += 2) {
    float x0 = h[(size_t)n * HID + c];
    float x1 = h[(size_t)(n + 1) * HID + c];
    m = fmaxf(m, fmaxf(x0, x1));
  }
  if (n < ce) m = fmaxf(m, h[(size_t)n * HID + c]);
  part[((size_t)gi * 8 + ck) * HID + c] = m;
}

__global__ __launch_bounds__(256) void k_pool2(const float* __restrict__ part,
                                               float* __restrict__ g) {
  int gi = blockIdx.x, c = (int)threadIdx.x;
  float m = part[((size_t)gi * 8) * HID + c];
  #pragma unroll
  for (int k = 1; k < 8; ++k) m = fmaxf(m, part[((size_t)gi * 8 + k) * HID + c]);
  g[gi * HID + c] = m;
}

__global__ __launch_bounds__(256) void k_classifier(const float* __restrict__ g,
                                                    const float* __restrict__ w1,
                                                    const float* __restrict__ b1,
                                                    const float* __restrict__ w2,
                                                    const float* __restrict__ b2,
                                                    float* __restrict__ out) {
  int gi = blockIdx.x, t = (int)threadIdx.x;
  __shared__ float gs[HID], zs[HID];
  gs[t] = g[gi * HID + t];
  __syncthreads();
  float s = b1[t];
  for (int k = 0; k < HID; ++k) s = fmaf(gs[k], w1[k * HID + t], s);
  zs[t] = fmaxf(s, 0.f);
  __syncthreads();
  if (t < 4) {
    float o = b2[t];
    for (int k = 0; k < HID; ++k) o = fmaf(zs[k], w2[k * 4 + t], o);
    out[gi * 4 + t] = o;
  }
}

// ---------------- launch ----------------
extern "C" void kernel_launch(void* const* d_in, const int* in_sizes, int n_in,
                              void* d_out, int out_size, void* d_ws, size_t ws_size,
                              hipStream_t stream) {
  const float* x      = (const float*)d_in[0];
  const int*   eidx   = (const int*)d_in[1];
  const int*   etype  = (const int*)d_in[2];
  const int*   batch  = (const int*)d_in[3];
  const float* in_w   = (const float*)d_in[4];
  const float* in_b   = (const float*)d_in[5];
  const float* root_w = (const float*)d_in[6];
  const float* rel_w  = (const float*)d_in[7];
  const float* conv_b = (const float*)d_in[8];
  const float* ln_w   = (const float*)d_in[9];
  const float* ln_b   = (const float*)d_in[10];
  const float* cls_w1 = (const float*)d_in[11];
  const float* cls_b1 = (const float*)d_in[12];
  const float* cls_w2 = (const float*)d_in[13];
  const float* cls_b2 = (const float*)d_in[14];
  float* out = (float*)d_out;

  char* ws = (char*)d_ws;
  size_t off = 0;
  auto alloc = [&](size_t bytes) -> void* {
    void* p = ws + off;
    off += (bytes + 255) & ~(size_t)255;
    return p;
  };
  float*    bufA   = (float*)alloc(sizeof(float) * (size_t)NN * HID);
  float*    bufB   = (float*)alloc(sizeof(float) * (size_t)NN * HID);
  unsigned short* hAh = (unsigned short*)alloc(sizeof(unsigned short) * (size_t)NN * HID);
  unsigned short* hAl = (unsigned short*)alloc(sizeof(unsigned short) * (size_t)NN * HID);
  unsigned short* hBh = (unsigned short*)alloc(sizeof(unsigned short) * (size_t)NN * HID);
  unsigned short* hBl = (unsigned short*)alloc(sizeof(unsigned short) * (size_t)NN * HID);
  unsigned short* aggH = (unsigned short*)alloc(sizeof(unsigned short) * (size_t)NN * NREL * HID);
  unsigned short* aggL = (unsigned short*)alloc(sizeof(unsigned short) * (size_t)NN * NREL * HID);
  unsigned* csr       = (unsigned*)alloc(sizeof(unsigned) * NE);
  int*      deg       = (int*)alloc(sizeof(int) * 53248);
  int*      row_start = (int*)alloc(sizeof(int) * (NN + 1));
  int*      cursor    = (int*)alloc(sizeof(int) * NN);
  int*      gstart    = (int*)alloc(sizeof(int) * (NG + 1));
  float*    gpool     = (float*)alloc(sizeof(float) * NG * HID);
  float*    gpart     = (float*)alloc(sizeof(float) * NG * 8 * HID);
  unsigned short* wInH = (unsigned short*)alloc(sizeof(unsigned short) * 96 * 256 * 8);
  unsigned short* wInL = (unsigned short*)alloc(sizeof(unsigned short) * 96 * 256 * 8);
  unsigned short* wLH[NLAY];
  unsigned short* wLL[NLAY];
  for (int L = 0; L < NLAY; ++L) {
    wLH[L] = (unsigned short*)alloc(sizeof(unsigned short) * 128 * 256 * 8);
    wLL[L] = (unsigned short*)alloc(sizeof(unsigned short) * 128 * 256 * 8);
  }
  (void)ws_size; (void)in_sizes; (void)n_in; (void)out_size;

  const int* esrc = eidx;
  const int* edst = eidx + NE;

  k_cvt<<<IND, 256, 0, stream>>>(in_w, IND, nullptr, IND, wInH, wInL);
  for (int L = 0; L < NLAY; ++L)
    k_cvt<<<HID + NREL * HID, 256, 0, stream>>>(
        root_w + (size_t)L * HID * HID, HID,
        rel_w + (size_t)L * NREL * HID * HID, HID + NREL * HID, wLH[L], wLL[L]);

  k_zero_int<<<(53248 + 255) / 256, 256, 0, stream>>>(deg, 53248);
  k_hist<<<(NE + 255) / 256, 256, 0, stream>>>(edst, deg);
  k_scan<<<1, 1024, 0, stream>>>(deg, row_start, cursor);
  k_scatter<<<(NE + 255) / 256, 256, 0, stream>>>(esrc, edst, etype, cursor, csr);
  k_graph_bounds<<<(NN + 255) / 256, 256, 0, stream>>>(batch, gstart);

  int gemm_grid = (NN + 63) / 64;   // 782
  k_gemm_in<<<gemm_grid, 256, 0, stream>>>(x, wInH, wInL, in_b, bufA, hAh, hAl, NN);

  float* hcur = bufA;  unsigned short* hch = hAh;  unsigned short* hcl = hAl;
  float* hnxt = bufB;  unsigned short* hnh = hBh;  unsigned short* hnl = hBl;
  for (int L = 0; L < NLAY; ++L) {
    k_aggregate<<<NN, 64, 0, stream>>>(hcur, row_start, csr, aggH, aggL);
    k_gemm_L<<<gemm_grid, 256, 0, stream>>>(
        hch, hcl, aggH, aggL, wLH[L], wLL[L],
        conv_b + L * HID, hcur, ln_w + L * HID, ln_b + L * HID,
        hnxt, hnh, hnl, NN);
    float* tf = hcur; hcur = hnxt; hnxt = tf;
    unsigned short* th = hch; hch = hnh; hnh = th;
    unsigned short* tl = hcl; hcl = hnl; hnl = tl;
  }

  k_pool1<<<dim3(NG, 8), 256, 0, stream>>>(hcur, gstart, gpart);
  k_pool2<<<NG, 256, 0, stream>>>(gpart, gpool);
  k_classifier<<<NG, 256, 0, stream>>>(gpool, cls_w1, cls_b1, cls_w2, cls_b2, out);
}